// Round 1
// baseline (464.616 us; speedup 1.0000x reference)
//
#include <hip/hip_runtime.h>
#include <cstdint>
#include <cstddef>

#define NPTS 21824
#define NB   64
#define NCLS 20
#define MAXN 150

// Levels: base, dim, log2(dim), stride
// L0: [0,16384)     dim=128 s=8
// L1: [16384,20480) dim=64  s=16
// L2: [20480,21504) dim=32  s=32
// L3: [21504,21760) dim=16  s=64
// L4: [21760,21824) dim=8   s=128

// ---------------------------------------------------------------------------
// K1: per-point score (sqrt(sigmoid(max cls)*sigmoid(ctr))) + argmax id
// ---------------------------------------------------------------------------
__global__ __launch_bounds__(256) void k_scores(
    const float* __restrict__ c0, const float* __restrict__ c1,
    const float* __restrict__ c2, const float* __restrict__ c3,
    const float* __restrict__ c4,
    const float* __restrict__ t0, const float* __restrict__ t1,
    const float* __restrict__ t2, const float* __restrict__ t3,
    const float* __restrict__ t4,
    float* __restrict__ scores, int* __restrict__ ids)
{
    int p = blockIdx.x * 256 + threadIdx.x;
    if (p >= NPTS) return;
    int b = blockIdx.y;

    const float* cp; const float* tp; int base, dim;
    if (p < 16384)      { cp = c0; tp = t0; base = 0;     dim = 128; }
    else if (p < 20480) { cp = c1; tp = t1; base = 16384; dim = 64;  }
    else if (p < 21504) { cp = c2; tp = t2; base = 20480; dim = 32;  }
    else if (p < 21760) { cp = c3; tp = t3; base = 21504; dim = 16;  }
    else                { cp = c4; tp = t4; base = 21760; dim = 8;   }

    int q = p - base;
    size_t hw = (size_t)dim * dim;
    const float* cb = cp + (size_t)b * NCLS * hw + q;

    // sigmoid per class, argmax over sigmoids (first max wins) — matches JAX
    float best = -1.0f; int bi = 0;
    for (int c = 0; c < NCLS; ++c) {
        float v  = cb[(size_t)c * hw];
        float sg = 1.0f / (1.0f + expf(-v));
        if (sg > best) { best = sg; bi = c; }
    }
    float ct  = tp[(size_t)b * hw + q];
    float sct = 1.0f / (1.0f + expf(-ct));

    scores[(size_t)b * NPTS + p] = sqrtf(__fmul_rn(best, sct));
    ids[(size_t)b * NPTS + p]    = bi + 1;
}

// ---------------------------------------------------------------------------
// K2: exact top-150 per batch via 64-bit-key radix select + bitonic sort.
// key = (score_bits << 32) | ~idx  -> distinct keys, JAX tie-break encoded.
// ---------------------------------------------------------------------------
__global__ __launch_bounds__(256) void k_topk(
    const float* __restrict__ scores,
    int* __restrict__ tk_idx, float* __restrict__ tk_sc)
{
    int b   = blockIdx.x;
    int tid = threadIdx.x;
    const float* s = scores + (size_t)b * NPTS;

    __shared__ unsigned int hist[256];
    __shared__ unsigned long long sh_prefix;
    __shared__ int sh_rank;
    __shared__ int sh_cnt;
    __shared__ unsigned long long keys[256];

    if (tid == 0) { sh_prefix = 0ull; sh_rank = MAXN; }
    __syncthreads();

    for (int pass = 0; pass < 8; ++pass) {
        int sh = 56 - pass * 8;
        hist[tid] = 0u;
        __syncthreads();
        unsigned long long prefix = sh_prefix;
        for (int p = tid; p < NPTS; p += 256) {
            unsigned int ub = __float_as_uint(s[p]);
            unsigned long long key =
                ((unsigned long long)ub << 32) | (unsigned int)(~p);
            bool ok = (pass == 0) || ((key >> (sh + 8)) == prefix);
            if (ok) atomicAdd(&hist[(unsigned)(key >> sh) & 255u], 1u);
        }
        __syncthreads();
        if (tid == 0) {
            int r = sh_rank, cum = 0, bsel = 0;
            for (int bin = 255; bin >= 0; --bin) {
                int c = (int)hist[bin];
                if (cum + c >= r) { bsel = bin; sh_rank = r - cum; break; }
                cum += c;
            }
            sh_prefix = (sh_prefix << 8) | (unsigned long long)(unsigned)bsel;
        }
        __syncthreads();
    }

    unsigned long long T = sh_prefix;   // exact 150th-largest key
    if (tid == 0) sh_cnt = 0;
    keys[tid] = 0ull;                   // pad
    __syncthreads();

    for (int p = tid; p < NPTS; p += 256) {
        unsigned int ub = __float_as_uint(s[p]);
        unsigned long long key =
            ((unsigned long long)ub << 32) | (unsigned int)(~p);
        if (key >= T) {
            int pos = atomicAdd(&sh_cnt, 1);
            if (pos < 256) keys[pos] = key;
        }
    }
    __syncthreads();

    // bitonic sort, 256 elems, descending
    for (int k = 2; k <= 256; k <<= 1) {
        for (int j = k >> 1; j > 0; j >>= 1) {
            int ixj = tid ^ j;
            if (ixj > tid) {
                unsigned long long a = keys[tid], c = keys[ixj];
                bool desc = ((tid & k) == 0);
                if (desc ? (a < c) : (a > c)) { keys[tid] = c; keys[ixj] = a; }
            }
            __syncthreads();
        }
    }

    if (tid < MAXN) {
        unsigned long long key = keys[tid];
        int p = (int)(~(unsigned int)key);
        if (p < 0 || p >= NPTS) p = 0;  // safety (unreachable if correct)
        tk_sc[b * MAXN + tid]  = __uint_as_float((unsigned int)(key >> 32));
        tk_idx[b * MAXN + tid] = p;
    }
}

// ---------------------------------------------------------------------------
// K3: decode 150 boxes, exact reference NMS (class-offset), write outputs
// ---------------------------------------------------------------------------
__global__ __launch_bounds__(256) void k_nms(
    const float* __restrict__ r0, const float* __restrict__ r1,
    const float* __restrict__ r2, const float* __restrict__ r3,
    const float* __restrict__ r4,
    const int* __restrict__ ids,
    const int* __restrict__ tk_idx, const float* __restrict__ tk_sc,
    float* __restrict__ out)
{
    int b   = blockIdx.x;
    int tid = threadIdx.x;

    __shared__ float bx0[MAXN], bx1[MAXN], bx2[MAXN], bx3[MAXN];
    __shared__ float ox1[MAXN], oy1[MAXN], ox2[MAXN], oy2[MAXN], area[MAXN];
    __shared__ float sc[MAXN];
    __shared__ int   idv[MAXN];
    __shared__ unsigned long long sup[MAXN][3];
    __shared__ unsigned long long keepw[3];
    __shared__ float shcmax;

    if (tid < MAXN) {
        int p = tk_idx[b * MAXN + tid];
        sc[tid]  = tk_sc[b * MAXN + tid];
        idv[tid] = ids[(size_t)b * NPTS + p];

        const float* rp; int base, dim, lg, st;
        if (p < 16384)      { rp = r0; base = 0;     dim = 128; lg = 7; st = 8;   }
        else if (p < 20480) { rp = r1; base = 16384; dim = 64;  lg = 6; st = 16;  }
        else if (p < 21504) { rp = r2; base = 20480; dim = 32;  lg = 5; st = 32;  }
        else if (p < 21760) { rp = r3; base = 21504; dim = 16;  lg = 4; st = 64;  }
        else                { rp = r4; base = 21760; dim = 8;   lg = 3; st = 128; }

        int q = p - base;
        int y = q >> lg;
        int x = q & (dim - 1);
        float s  = (float)st;
        float cx = (float)(x * st + (st >> 1));   // exact small ints
        float cy = (float)(y * st + (st >> 1));
        size_t hw = (size_t)dim * dim;
        const float* rg = rp + (size_t)b * 4 * hw + q;
        float a0 = rg[0], a1 = rg[hw], a2 = rg[2 * hw], a3 = rg[3 * hw];
        // match XLA's unfused mul-then-add rounding
        bx0[tid] = __fsub_rn(cx, __fmul_rn(a0, s));
        bx1[tid] = __fsub_rn(cy, __fmul_rn(a1, s));
        bx2[tid] = __fadd_rn(cx, __fmul_rn(a2, s));
        bx3[tid] = __fadd_rn(cy, __fmul_rn(a3, s));
    }
    __syncthreads();

    if (tid == 0) {
        float m = -INFINITY;
        for (int k = 0; k < MAXN; ++k) {
            if (sc[k] > 0.05f) {
                m = fmaxf(m, fmaxf(fmaxf(bx0[k], bx1[k]),
                                   fmaxf(bx2[k], bx3[k])));
            }
        }
        shcmax = isfinite(m) ? m : 0.0f;
    }
    __syncthreads();

    float cm1 = __fadd_rn(shcmax, 1.0f);
    if (tid < MAXN) {
        float off = __fmul_rn((float)idv[tid], cm1);
        float X1 = __fadd_rn(bx0[tid], off);
        float Y1 = __fadd_rn(bx1[tid], off);
        float X2 = __fadd_rn(bx2[tid], off);
        float Y2 = __fadd_rn(bx3[tid], off);
        ox1[tid] = X1; oy1[tid] = Y1; ox2[tid] = X2; oy2[tid] = Y2;
        area[tid] = __fmul_rn(__fadd_rn(__fsub_rn(X2, X1), 1.0f),
                              __fadd_rn(__fsub_rn(Y2, Y1), 1.0f));
    }
    __syncthreads();

    // suppression bitmask: task t -> (row i, 64-col word w)
    for (int t = tid; t < MAXN * 3; t += 256) {
        int i = t / 3;
        int w = t - i * 3;
        float x1i = ox1[i], y1i = oy1[i], x2i = ox2[i], y2i = oy2[i], ai = area[i];
        unsigned long long bits = 0ull;
        for (int bi = 0; bi < 64; ++bi) {
            int j = w * 64 + bi;
            if (j >= MAXN) break;
            float xmin = fmaxf(x1i, ox1[j]);
            float ymin = fmaxf(y1i, oy1[j]);
            float xmax = fminf(x2i, ox2[j]);
            float ymax = fminf(y2i, oy2[j]);
            float ow = fmaxf(__fsub_rn(xmax, xmin), 0.0f);
            float oh = fmaxf(__fsub_rn(ymax, ymin), 0.0f);
            float ov = __fmul_rn(ow, oh);
            float un = fmaxf(__fsub_rn(__fadd_rn(ai, area[j]), ov), 1e-10f);
            float iou = __fdiv_rn(ov, un);
            if (iou > 0.6f) bits |= (1ull << bi);
        }
        sup[i][w] = bits;
    }
    __syncthreads();

    if (tid == 0) {
        unsigned long long kw[3] = {0ull, 0ull, 0ull};
        for (int k = 0; k < MAXN; ++k)
            if (sc[k] > 0.05f) kw[k >> 6] |= 1ull << (k & 63);
        for (int i = 0; i < MAXN; ++i) {
            if ((kw[i >> 6] >> (i & 63)) & 1ull) {
                for (int w = 0; w < 3; ++w) {
                    int lo = w * 64;
                    unsigned long long allow;
                    if (i < lo)            allow = ~0ull;
                    else if (i >= lo + 63) allow = 0ull;
                    else allow = ~((1ull << (i - lo + 1)) - 1ull);
                    kw[w] &= ~(sup[i][w] & allow);
                }
            }
        }
        keepw[0] = kw[0]; keepw[1] = kw[1]; keepw[2] = kw[2];
    }
    __syncthreads();

    if (tid < MAXN) {
        bool kp = (keepw[tid >> 6] >> (tid & 63)) & 1ull;
        int o = b * MAXN + tid;
        float* oSc = out;
        float* oId = out + NB * MAXN;
        float* oBx = out + 2 * NB * MAXN;
        float* oKp = out + 2 * NB * MAXN + NB * MAXN * 4;
        oSc[o] = kp ? sc[tid] : 0.0f;
        oId[o] = kp ? (float)idv[tid] : 0.0f;
        oBx[o * 4 + 0] = kp ? bx0[tid] : 0.0f;
        oBx[o * 4 + 1] = kp ? bx1[tid] : 0.0f;
        oBx[o * 4 + 2] = kp ? bx2[tid] : 0.0f;
        oBx[o * 4 + 3] = kp ? bx3[tid] : 0.0f;
        oKp[o] = kp ? 1.0f : 0.0f;
    }
}

// ---------------------------------------------------------------------------
extern "C" void kernel_launch(void* const* d_in, const int* in_sizes, int n_in,
                              void* d_out, int out_size, void* d_ws, size_t ws_size,
                              hipStream_t stream)
{
    // setup_inputs dict order: cls0, reg0, ctr0, cls1, reg1, ctr1, ...
    const float* cls[5]; const float* reg[5]; const float* ctr[5];
    for (int li = 0; li < 5; ++li) {
        cls[li] = (const float*)d_in[3 * li + 0];
        reg[li] = (const float*)d_in[3 * li + 1];
        ctr[li] = (const float*)d_in[3 * li + 2];
    }

    char* ws = (char*)d_ws;
    float* scores = (float*)ws;                                   // B*NPTS f32
    int*   ids    = (int*)(ws + (size_t)NB * NPTS * 4);           // B*NPTS i32
    int*   tk_idx = (int*)(ws + (size_t)NB * NPTS * 8);           // B*150 i32
    float* tk_sc  = (float*)(ws + (size_t)NB * NPTS * 8
                                + (size_t)NB * MAXN * 4);         // B*150 f32

    dim3 g1((NPTS + 255) / 256, NB);
    k_scores<<<g1, 256, 0, stream>>>(cls[0], cls[1], cls[2], cls[3], cls[4],
                                     ctr[0], ctr[1], ctr[2], ctr[3], ctr[4],
                                     scores, ids);
    k_topk<<<NB, 256, 0, stream>>>(scores, tk_idx, tk_sc);
    k_nms<<<NB, 256, 0, stream>>>(reg[0], reg[1], reg[2], reg[3], reg[4],
                                  ids, tk_idx, tk_sc, (float*)d_out);
}

// Round 2
// 287.858 us; speedup vs baseline: 1.6140x; 1.6140x over previous
//
#include <hip/hip_runtime.h>
#include <cstdint>
#include <cstddef>

#define NPTS 21824
#define NB   64
#define NCLS 20
#define MAXN 150
#define NCHUNK 11
#define CHSZ 2048

typedef unsigned long long u64;
typedef unsigned int u32;

// Levels: L0 [0,16384) d=128 s=8 | L1 [16384,20480) d=64 s=16
//         L2 [20480,21504) d=32 s=32 | L3 [21504,21760) d=16 s=64
//         L4 [21760,21824) d=8 s=128

// ---------------------------------------------------------------------------
// Exact top-k threshold via 6-pass byte radix select over LDS keys.
// Keys must be distinct in their high 48 bits (ours are: p is unique).
// Returns T such that exactly k keys satisfy key >= T.
// All 256 threads must call. Uses caller-provided LDS scratch.
// ---------------------------------------------------------------------------
__device__ __forceinline__ u64 radix_select_top(
    const u64* __restrict__ keys, int n, int k0,
    u32* hist, u32* suf, u64* shp, int* shr, int* shb)
{
    int tid = threadIdx.x;
    if (tid == 0) { *shp = 0ull; *shr = k0; }
    __syncthreads();
    for (int pass = 0; pass < 6; ++pass) {
        int sh = 56 - pass * 8;
        hist[tid] = 0u;
        __syncthreads();
        u64 prefix = *shp;
        int r = *shr;
        for (int i = tid; i < n; i += 256) {
            u64 key = keys[i];
            bool ok = (pass == 0) || ((key >> (sh + 8)) == prefix);
            if (ok) atomicAdd(&hist[(u32)(key >> sh) & 255u], 1u);
        }
        __syncthreads();
        suf[tid] = hist[tid];
        __syncthreads();
        // parallel suffix sum: suf[t] = sum hist[t..255]
        for (int d = 1; d < 256; d <<= 1) {
            u32 v = (tid + d < 256) ? suf[tid + d] : 0u;
            __syncthreads();
            suf[tid] += v;
            __syncthreads();
        }
        u32 nxt = (tid == 255) ? 0u : suf[tid + 1];
        if (suf[tid] >= (u32)r && nxt < (u32)r) {
            *shb = tid;
            *shr = r - (int)nxt;
        }
        __syncthreads();
        if (tid == 0) *shp = (prefix << 8) | (u64)(u32)(*shb);
        __syncthreads();
    }
    u64 T = (*shp) << 16;
    __syncthreads();
    return T;
}

// ---------------------------------------------------------------------------
// K1: fused scores + per-(batch,chunk) exact top-150.
// key = score_bits<<32 | (21823-p)<<17 | id<<12  (id in dead bits; p unique)
// ---------------------------------------------------------------------------
__global__ __launch_bounds__(256) void k_part(
    const float* __restrict__ c0, const float* __restrict__ c1,
    const float* __restrict__ c2, const float* __restrict__ c3,
    const float* __restrict__ c4,
    const float* __restrict__ t0, const float* __restrict__ t1,
    const float* __restrict__ t2, const float* __restrict__ t3,
    const float* __restrict__ t4,
    u64* __restrict__ cand)
{
    __shared__ u64 keys[CHSZ];
    __shared__ u32 hist[256], suf[256];
    __shared__ u64 shp; __shared__ int shr, shb, shcnt;

    const int tid   = threadIdx.x;
    const int chunk = blockIdx.x;
    const int b     = blockIdx.y;
    const int cbase = chunk * CHSZ;

    for (int half = 0; half < 2; ++half) {
        int pl = half * 1024 + tid * 4;       // local idx (4-aligned pack)
        int p  = cbase + pl;
        u64 kk0 = 0, kk1 = 0, kk2 = 0, kk3 = 0;
        if (p < NPTS) {
            const float* cp; const float* tp; int base; size_t hw;
            if (p < 16384)      { cp = c0; tp = t0; base = 0;     hw = 16384; }
            else if (p < 20480) { cp = c1; tp = t1; base = 16384; hw = 4096;  }
            else if (p < 21504) { cp = c2; tp = t2; base = 20480; hw = 1024;  }
            else if (p < 21760) { cp = c3; tp = t3; base = 21504; hw = 256;   }
            else                { cp = c4; tp = t4; base = 21760; hw = 64;    }
            int q = p - base;                 // 4-aligned (all bases are)
            const float* cb = cp + (size_t)b * NCLS * hw + q;

            float best0 = -1.f, best1 = -1.f, best2 = -1.f, best3 = -1.f;
            int   bi0 = 0, bi1 = 0, bi2 = 0, bi3 = 0;
            for (int c = 0; c < NCLS; ++c) {
                const float4 v = *reinterpret_cast<const float4*>(cb + (size_t)c * hw);
                float sg;
                sg = 1.0f / (1.0f + expf(-v.x)); if (sg > best0) { best0 = sg; bi0 = c; }
                sg = 1.0f / (1.0f + expf(-v.y)); if (sg > best1) { best1 = sg; bi1 = c; }
                sg = 1.0f / (1.0f + expf(-v.z)); if (sg > best2) { best2 = sg; bi2 = c; }
                sg = 1.0f / (1.0f + expf(-v.w)); if (sg > best3) { best3 = sg; bi3 = c; }
            }
            const float4 cv = *reinterpret_cast<const float4*>(tp + (size_t)b * hw + q);
            float sct, sc;
            sct = 1.0f / (1.0f + expf(-cv.x)); sc = sqrtf(__fmul_rn(best0, sct));
            kk0 = ((u64)__float_as_uint(sc) << 32) | ((u64)(u32)(21823 - p)     << 17) | ((u64)(u32)(bi0 + 1) << 12);
            sct = 1.0f / (1.0f + expf(-cv.y)); sc = sqrtf(__fmul_rn(best1, sct));
            kk1 = ((u64)__float_as_uint(sc) << 32) | ((u64)(u32)(21823 - (p+1)) << 17) | ((u64)(u32)(bi1 + 1) << 12);
            sct = 1.0f / (1.0f + expf(-cv.z)); sc = sqrtf(__fmul_rn(best2, sct));
            kk2 = ((u64)__float_as_uint(sc) << 32) | ((u64)(u32)(21823 - (p+2)) << 17) | ((u64)(u32)(bi2 + 1) << 12);
            sct = 1.0f / (1.0f + expf(-cv.w)); sc = sqrtf(__fmul_rn(best3, sct));
            kk3 = ((u64)__float_as_uint(sc) << 32) | ((u64)(u32)(21823 - (p+3)) << 17) | ((u64)(u32)(bi3 + 1) << 12);
        }
        keys[pl + 0] = kk0; keys[pl + 1] = kk1;
        keys[pl + 2] = kk2; keys[pl + 3] = kk3;
    }
    __syncthreads();

    u64 T = radix_select_top(keys, CHSZ, MAXN, hist, suf, &shp, &shr, &shb);
    if (tid == 0) shcnt = 0;
    __syncthreads();

    u64* outp = cand + ((size_t)b * NCHUNK + chunk) * MAXN;
    for (int i = tid; i < CHSZ; i += 256) {
        u64 key = keys[i];
        if (key >= T) {
            int pos = atomicAdd(&shcnt, 1);
            if (pos < MAXN) outp[pos] = key;   // exactly MAXN by construction
        }
    }
}

// ---------------------------------------------------------------------------
// K2: merge 11x150 candidates -> exact global top-150 (sorted), decode boxes,
// reference-exact class-offset NMS, write outputs.
// ---------------------------------------------------------------------------
__global__ __launch_bounds__(256) void k_final(
    const float* __restrict__ r0, const float* __restrict__ r1,
    const float* __restrict__ r2, const float* __restrict__ r3,
    const float* __restrict__ r4,
    const u64* __restrict__ cand,
    float* __restrict__ out)
{
    const int NC2 = NCHUNK * MAXN;   // 1650
    __shared__ u64 ck[NCHUNK * MAXN];
    __shared__ u32 hist[256], suf[256];
    __shared__ u64 shp; __shared__ int shr, shb, shcnt;
    __shared__ u64 win[MAXN], srt[MAXN];
    __shared__ float bx0[MAXN], bx1[MAXN], bx2[MAXN], bx3[MAXN];
    __shared__ float ox1[MAXN], oy1[MAXN], ox2[MAXN], oy2[MAXN], area[MAXN];
    __shared__ float sc[MAXN];
    __shared__ int   idv[MAXN];
    __shared__ u64 sup[MAXN][3];
    __shared__ u64 keepw[3];
    __shared__ float shcmax;
    __shared__ float wmax[4];

    const int b = blockIdx.x, tid = threadIdx.x;

    for (int i = tid; i < NC2; i += 256) ck[i] = cand[(size_t)b * NC2 + i];
    __syncthreads();

    u64 T = radix_select_top(ck, NC2, MAXN, hist, suf, &shp, &shr, &shb);
    if (tid == 0) shcnt = 0;
    __syncthreads();
    for (int i = tid; i < NC2; i += 256) {
        u64 key = ck[i];
        if (key >= T) {
            int pos = atomicAdd(&shcnt, 1);
            if (pos < MAXN) win[pos] = key;
        }
    }
    __syncthreads();

    // rank-sort 150 distinct keys (descending); broadcast-friendly LDS reads
    if (tid < MAXN) {
        u64 mk = win[tid]; int r = 0;
        for (int j = 0; j < MAXN; ++j) r += (win[j] > mk);
        srt[r] = mk;
    }
    __syncthreads();

    // decode selected boxes
    if (tid < MAXN) {
        u64 key = srt[tid];
        sc[tid]  = __uint_as_float((u32)(key >> 32));
        int p    = 21823 - (int)((key >> 17) & 0x7FFFu);
        idv[tid] = (int)((key >> 12) & 31u);

        const float* rp; int base, dim, lg, st;
        if (p < 16384)      { rp = r0; base = 0;     dim = 128; lg = 7; st = 8;   }
        else if (p < 20480) { rp = r1; base = 16384; dim = 64;  lg = 6; st = 16;  }
        else if (p < 21504) { rp = r2; base = 20480; dim = 32;  lg = 5; st = 32;  }
        else if (p < 21760) { rp = r3; base = 21504; dim = 16;  lg = 4; st = 64;  }
        else                { rp = r4; base = 21760; dim = 8;   lg = 3; st = 128; }

        int q = p - base;
        int y = q >> lg;
        int x = q & (dim - 1);
        float s  = (float)st;
        float cx = (float)(x * st + (st >> 1));
        float cy = (float)(y * st + (st >> 1));
        size_t hw = (size_t)dim * dim;
        const float* rg = rp + (size_t)b * 4 * hw + q;
        float a0 = rg[0], a1 = rg[hw], a2 = rg[2 * hw], a3 = rg[3 * hw];
        bx0[tid] = __fsub_rn(cx, __fmul_rn(a0, s));
        bx1[tid] = __fsub_rn(cy, __fmul_rn(a1, s));
        bx2[tid] = __fadd_rn(cx, __fmul_rn(a2, s));
        bx3[tid] = __fadd_rn(cy, __fmul_rn(a3, s));
    }
    __syncthreads();

    // coord_max over valid boxes — parallel shuffle reduce
    float m = -INFINITY;
    if (tid < MAXN && sc[tid] > 0.05f)
        m = fmaxf(fmaxf(bx0[tid], bx1[tid]), fmaxf(bx2[tid], bx3[tid]));
    #pragma unroll
    for (int off = 32; off >= 1; off >>= 1) m = fmaxf(m, __shfl_xor(m, off));
    if ((tid & 63) == 0) wmax[tid >> 6] = m;
    __syncthreads();
    if (tid == 0) {
        float mm = fmaxf(fmaxf(wmax[0], wmax[1]), fmaxf(wmax[2], wmax[3]));
        shcmax = isfinite(mm) ? mm : 0.0f;
    }
    __syncthreads();

    float cm1 = __fadd_rn(shcmax, 1.0f);
    if (tid < MAXN) {
        float off = __fmul_rn((float)idv[tid], cm1);
        float X1 = __fadd_rn(bx0[tid], off);
        float Y1 = __fadd_rn(bx1[tid], off);
        float X2 = __fadd_rn(bx2[tid], off);
        float Y2 = __fadd_rn(bx3[tid], off);
        ox1[tid] = X1; oy1[tid] = Y1; ox2[tid] = X2; oy2[tid] = Y2;
        area[tid] = __fmul_rn(__fadd_rn(__fsub_rn(X2, X1), 1.0f),
                              __fadd_rn(__fsub_rn(Y2, Y1), 1.0f));
    }
    __syncthreads();

    // suppression bitmask rows
    for (int t = tid; t < MAXN * 3; t += 256) {
        int i = t / 3;
        int w = t - i * 3;
        float x1i = ox1[i], y1i = oy1[i], x2i = ox2[i], y2i = oy2[i], ai = area[i];
        u64 bits = 0ull;
        for (int e = 0; e < 64; ++e) {
            int j = w * 64 + e;
            if (j >= MAXN) break;
            float xmin = fmaxf(x1i, ox1[j]);
            float ymin = fmaxf(y1i, oy1[j]);
            float xmax = fminf(x2i, ox2[j]);
            float ymax = fminf(y2i, oy2[j]);
            float ow = fmaxf(__fsub_rn(xmax, xmin), 0.0f);
            float oh = fmaxf(__fsub_rn(ymax, ymin), 0.0f);
            float ov = __fmul_rn(ow, oh);
            float un = fmaxf(__fsub_rn(__fadd_rn(ai, area[j]), ov), 1e-10f);
            float iou = __fdiv_rn(ov, un);
            if (iou > 0.6f) bits |= (1ull << e);
        }
        sup[i][w] = bits;
    }
    __syncthreads();

    // greedy suppression, register-resident masks + one-ahead LDS prefetch
    if (tid == 0) {
        u64 kw0 = 0, kw1 = 0, kw2 = 0;
        for (int k = 0; k < MAXN; ++k) {
            if (sc[k] > 0.05f) {
                if (k < 64)       kw0 |= 1ull << k;
                else if (k < 128) kw1 |= 1ull << (k - 64);
                else              kw2 |= 1ull << (k - 128);
            }
        }
        u64 s0 = sup[0][0], s1 = sup[0][1], s2 = sup[0][2];
        for (int i = 0; i < MAXN; ++i) {
            u64 n0 = 0, n1 = 0, n2 = 0;
            if (i + 1 < MAXN) { n0 = sup[i+1][0]; n1 = sup[i+1][1]; n2 = sup[i+1][2]; }
            bool kept = (i < 64) ? ((kw0 >> i) & 1ull)
                      : (i < 128) ? ((kw1 >> (i - 64)) & 1ull)
                                  : ((kw2 >> (i - 128)) & 1ull);
            if (kept) {
                u64 a0, a1, a2;
                if (i < 63)        { a0 = ~((1ull << (i + 1)) - 1ull); a1 = ~0ull; a2 = ~0ull; }
                else if (i == 63)  { a0 = 0ull; a1 = ~0ull; a2 = ~0ull; }
                else if (i < 127)  { a0 = 0ull; a1 = ~((1ull << (i - 63)) - 1ull); a2 = ~0ull; }
                else if (i == 127) { a0 = 0ull; a1 = 0ull; a2 = ~0ull; }
                else               { a0 = 0ull; a1 = 0ull; a2 = ~((1ull << (i - 127)) - 1ull); }
                kw0 &= ~(s0 & a0); kw1 &= ~(s1 & a1); kw2 &= ~(s2 & a2);
            }
            s0 = n0; s1 = n1; s2 = n2;
        }
        keepw[0] = kw0; keepw[1] = kw1; keepw[2] = kw2;
    }
    __syncthreads();

    if (tid < MAXN) {
        bool kp = (keepw[tid >> 6] >> (tid & 63)) & 1ull;
        int o = b * MAXN + tid;
        float* oSc = out;
        float* oId = out + NB * MAXN;
        float* oBx = out + 2 * NB * MAXN;
        float* oKp = out + 2 * NB * MAXN + NB * MAXN * 4;
        oSc[o] = kp ? sc[tid] : 0.0f;
        oId[o] = kp ? (float)idv[tid] : 0.0f;
        oBx[o * 4 + 0] = kp ? bx0[tid] : 0.0f;
        oBx[o * 4 + 1] = kp ? bx1[tid] : 0.0f;
        oBx[o * 4 + 2] = kp ? bx2[tid] : 0.0f;
        oBx[o * 4 + 3] = kp ? bx3[tid] : 0.0f;
        oKp[o] = kp ? 1.0f : 0.0f;
    }
}

// ---------------------------------------------------------------------------
extern "C" void kernel_launch(void* const* d_in, const int* in_sizes, int n_in,
                              void* d_out, int out_size, void* d_ws, size_t ws_size,
                              hipStream_t stream)
{
    const float* cls[5]; const float* reg[5]; const float* ctr[5];
    for (int li = 0; li < 5; ++li) {
        cls[li] = (const float*)d_in[3 * li + 0];
        reg[li] = (const float*)d_in[3 * li + 1];
        ctr[li] = (const float*)d_in[3 * li + 2];
    }

    u64* cand = (u64*)d_ws;   // NB * NCHUNK * MAXN u64 = 825 KB

    dim3 g1(NCHUNK, NB);
    k_part<<<g1, 256, 0, stream>>>(cls[0], cls[1], cls[2], cls[3], cls[4],
                                   ctr[0], ctr[1], ctr[2], ctr[3], ctr[4],
                                   cand);
    k_final<<<NB, 256, 0, stream>>>(reg[0], reg[1], reg[2], reg[3], reg[4],
                                    cand, (float*)d_out);
}

// Round 4
// 270.930 us; speedup vs baseline: 1.7149x; 1.0625x over previous
//
#include <hip/hip_runtime.h>
#include <cstdint>
#include <cstddef>

#define NPTS 21824
#define NB   64
#define NCLS 20
#define MAXN 150
#define NCHUNK 11
#define CHSZ 2048

typedef unsigned long long u64;
typedef unsigned int u32;

// Levels: L0 [0,16384) d=128 s=8 | L1 [16384,20480) d=64 s=16
//         L2 [20480,21504) d=32 s=32 | L3 [21504,21760) d=16 s=64
//         L4 [21760,21824) d=8 s=128

// ---------------------------------------------------------------------------
// In-place bitonic sort of 2048 u64 keys in LDS, descending. T = blockDim.
// 66 substeps, 1 barrier each, no atomics. Keys must be distinct (ours are:
// unique point index in low bits). Pad slots = 0 (sort to the bottom).
// ---------------------------------------------------------------------------
template<int T>
__device__ __forceinline__ void bitonic2048_desc(u64* keys)
{
    const int tid = threadIdx.x;
    for (int k = 2; k <= 2048; k <<= 1) {
        for (int j = k >> 1; j > 0; j >>= 1) {
            __syncthreads();
            #pragma unroll
            for (int t = tid; t < 1024; t += T) {
                int i = ((t & ~(j - 1)) << 1) | (t & (j - 1));
                int pr = i | j;
                u64 a = keys[i], c = keys[pr];
                bool desc = ((i & k) == 0);
                if (desc ? (a < c) : (a > c)) { keys[i] = c; keys[pr] = a; }
            }
        }
    }
    __syncthreads();
}

// ---------------------------------------------------------------------------
// K1: fused scores + per-(batch,chunk) exact top-150 via bitonic sort.
// key = score_bits<<32 | (21823-p).  max_c sigmoid(x_c) computed bit-exactly
// as 1/(1+min_c expf(-x_c))  (1/(1+u) monotone non-increasing in u).
// ---------------------------------------------------------------------------
__global__ __launch_bounds__(512) void k_part(
    const float* __restrict__ c0, const float* __restrict__ c1,
    const float* __restrict__ c2, const float* __restrict__ c3,
    const float* __restrict__ c4,
    const float* __restrict__ t0, const float* __restrict__ t1,
    const float* __restrict__ t2, const float* __restrict__ t3,
    const float* __restrict__ t4,
    u64* __restrict__ cand)
{
    __shared__ u64 keys[CHSZ];
    const int tid   = threadIdx.x;
    const int chunk = blockIdx.x;
    const int b     = blockIdx.y;

    const int pl = tid * 4;              // 4 contiguous points per thread
    const int p  = chunk * CHSZ + pl;
    u64 kk0 = 0, kk1 = 0, kk2 = 0, kk3 = 0;
    if (p < NPTS) {
        const float* cp; const float* tp; int base; size_t hw;
        if (p < 16384)      { cp = c0; tp = t0; base = 0;     hw = 16384; }
        else if (p < 20480) { cp = c1; tp = t1; base = 16384; hw = 4096;  }
        else if (p < 21504) { cp = c2; tp = t2; base = 20480; hw = 1024;  }
        else if (p < 21760) { cp = c3; tp = t3; base = 21504; hw = 256;   }
        else                { cp = c4; tp = t4; base = 21760; hw = 64;    }
        int q = p - base;                // 4-aligned (all bases are)
        const float* cb = cp + (size_t)b * NCLS * hw + q;

        float u0 = INFINITY, u1 = INFINITY, u2 = INFINITY, u3 = INFINITY;
        for (int c = 0; c < NCLS; ++c) {
            const float4 v = *reinterpret_cast<const float4*>(cb + (size_t)c * hw);
            u0 = fminf(u0, expf(-v.x));
            u1 = fminf(u1, expf(-v.y));
            u2 = fminf(u2, expf(-v.z));
            u3 = fminf(u3, expf(-v.w));
        }
        const float4 cv = *reinterpret_cast<const float4*>(tp + (size_t)b * hw + q);
        float best, sct, sc;
        best = 1.0f / (1.0f + u0); sct = 1.0f / (1.0f + expf(-cv.x));
        sc = sqrtf(__fmul_rn(best, sct));
        kk0 = ((u64)__float_as_uint(sc) << 32) | (u32)(21823 - p);
        best = 1.0f / (1.0f + u1); sct = 1.0f / (1.0f + expf(-cv.y));
        sc = sqrtf(__fmul_rn(best, sct));
        kk1 = ((u64)__float_as_uint(sc) << 32) | (u32)(21823 - (p + 1));
        best = 1.0f / (1.0f + u2); sct = 1.0f / (1.0f + expf(-cv.z));
        sc = sqrtf(__fmul_rn(best, sct));
        kk2 = ((u64)__float_as_uint(sc) << 32) | (u32)(21823 - (p + 2));
        best = 1.0f / (1.0f + u3); sct = 1.0f / (1.0f + expf(-cv.w));
        sc = sqrtf(__fmul_rn(best, sct));
        kk3 = ((u64)__float_as_uint(sc) << 32) | (u32)(21823 - (p + 3));
    }
    keys[pl + 0] = kk0; keys[pl + 1] = kk1;
    keys[pl + 2] = kk2; keys[pl + 3] = kk3;

    bitonic2048_desc<512>(keys);

    if (tid < MAXN)
        cand[((size_t)b * NCHUNK + chunk) * MAXN + tid] = keys[tid];
}

// ---------------------------------------------------------------------------
// K2: merge 11x150 -> global top-150 (bitonic), exact id recompute, decode,
// reference-exact class-offset NMS, outputs.
// ---------------------------------------------------------------------------
__global__ __launch_bounds__(1024) void k_final(
    const float* __restrict__ c0, const float* __restrict__ c1,
    const float* __restrict__ c2, const float* __restrict__ c3,
    const float* __restrict__ c4,
    const float* __restrict__ r0, const float* __restrict__ r1,
    const float* __restrict__ r2, const float* __restrict__ r3,
    const float* __restrict__ r4,
    const u64* __restrict__ cand,
    float* __restrict__ out)
{
    const int NC2 = NCHUNK * MAXN;   // 1650
    __shared__ u64 keys[CHSZ];
    __shared__ float bx0[MAXN], bx1[MAXN], bx2[MAXN], bx3[MAXN];
    __shared__ float ox1[MAXN], oy1[MAXN], ox2[MAXN], oy2[MAXN], area[MAXN];
    __shared__ float sc[MAXN];
    __shared__ int   idv[MAXN];
    __shared__ u64 sup[MAXN][3];
    __shared__ u64 keepw[3];
    __shared__ float shcmax;
    __shared__ float wmax[16];

    const int b = blockIdx.x, tid = threadIdx.x;

    for (int i = tid; i < CHSZ; i += 1024)
        keys[i] = (i < NC2) ? cand[(size_t)b * NC2 + i] : 0ull;

    bitonic2048_desc<1024>(keys);    // keys[0..149] = sorted global top-150

    // decode + exact id recompute for the 150 winners
    if (tid < MAXN) {
        u64 key = keys[tid];
        sc[tid] = __uint_as_float((u32)(key >> 32));
        int p   = 21823 - (int)(key & 0x7FFFu);

        const float* rp; const float* cp; int base, dim, lg, st;
        if (p < 16384)      { rp = r0; cp = c0; base = 0;     dim = 128; lg = 7; st = 8;   }
        else if (p < 20480) { rp = r1; cp = c1; base = 16384; dim = 64;  lg = 6; st = 16;  }
        else if (p < 21504) { rp = r2; cp = c2; base = 20480; dim = 32;  lg = 5; st = 32;  }
        else if (p < 21760) { rp = r3; cp = c3; base = 21504; dim = 16;  lg = 4; st = 64;  }
        else                { rp = r4; cp = c4; base = 21760; dim = 8;   lg = 3; st = 128; }

        int q = p - base;
        size_t hw = (size_t)dim * dim;

        // exact argmax over sigmoids, first max wins (reference semantics)
        const float* cb = cp + (size_t)b * NCLS * hw + q;
        float best = -1.0f; int bi = 0;
        for (int c = 0; c < NCLS; ++c) {
            float v  = cb[(size_t)c * hw];
            float sg = 1.0f / (1.0f + expf(-v));
            if (sg > best) { best = sg; bi = c; }
        }
        idv[tid] = bi + 1;

        int y = q >> lg;
        int x = q & (dim - 1);
        float s  = (float)st;
        float cx = (float)(x * st + (st >> 1));
        float cy = (float)(y * st + (st >> 1));
        const float* rg = rp + (size_t)b * 4 * hw + q;
        float a0 = rg[0], a1 = rg[hw], a2 = rg[2 * hw], a3 = rg[3 * hw];
        bx0[tid] = __fsub_rn(cx, __fmul_rn(a0, s));
        bx1[tid] = __fsub_rn(cy, __fmul_rn(a1, s));
        bx2[tid] = __fadd_rn(cx, __fmul_rn(a2, s));
        bx3[tid] = __fadd_rn(cy, __fmul_rn(a3, s));
    }
    __syncthreads();

    // coord_max over valid boxes — shuffle reduce, 16 wave maxes
    float m = -INFINITY;
    if (tid < MAXN && sc[tid] > 0.05f)
        m = fmaxf(fmaxf(bx0[tid], bx1[tid]), fmaxf(bx2[tid], bx3[tid]));
    #pragma unroll
    for (int off = 32; off >= 1; off >>= 1) m = fmaxf(m, __shfl_xor(m, off));
    if ((tid & 63) == 0) wmax[tid >> 6] = m;
    // valid mask via ballot (waves 0..2)
    if (tid < 192) {
        bool val = (tid < MAXN) && (sc[tid] > 0.05f);
        u64 mask = __ballot(val);
        if ((tid & 63) == 0) keepw[tid >> 6] = mask;
    }
    __syncthreads();
    if (tid == 0) {
        float mm = -INFINITY;
        for (int w = 0; w < 16; ++w) mm = fmaxf(mm, wmax[w]);
        shcmax = isfinite(mm) ? mm : 0.0f;
    }
    __syncthreads();

    float cm1 = __fadd_rn(shcmax, 1.0f);
    if (tid < MAXN) {
        float off = __fmul_rn((float)idv[tid], cm1);
        float X1 = __fadd_rn(bx0[tid], off);
        float Y1 = __fadd_rn(bx1[tid], off);
        float X2 = __fadd_rn(bx2[tid], off);
        float Y2 = __fadd_rn(bx3[tid], off);
        ox1[tid] = X1; oy1[tid] = Y1; ox2[tid] = X2; oy2[tid] = Y2;
        area[tid] = __fmul_rn(__fadd_rn(__fsub_rn(X2, X1), 1.0f),
                              __fadd_rn(__fsub_rn(Y2, Y1), 1.0f));
    }
    __syncthreads();

    // suppression bitmask rows: 450 tasks, one pass
    if (tid < MAXN * 3) {
        int i = tid / 3;
        int w = tid - i * 3;
        float x1i = ox1[i], y1i = oy1[i], x2i = ox2[i], y2i = oy2[i], ai = area[i];
        u64 bits = 0ull;
        for (int e = 0; e < 64; ++e) {
            int j = w * 64 + e;
            if (j >= MAXN) break;
            float xmin = fmaxf(x1i, ox1[j]);
            float ymin = fmaxf(y1i, oy1[j]);
            float xmax = fminf(x2i, ox2[j]);
            float ymax = fminf(y2i, oy2[j]);
            float ow = fmaxf(__fsub_rn(xmax, xmin), 0.0f);
            float oh = fmaxf(__fsub_rn(ymax, ymin), 0.0f);
            float ov = __fmul_rn(ow, oh);
            float un = fmaxf(__fsub_rn(__fadd_rn(ai, area[j]), ov), 1e-10f);
            float iou = __fdiv_rn(ov, un);
            if (iou > 0.6f) bits |= (1ull << e);
        }
        sup[i][w] = bits;
    }
    __syncthreads();

    // greedy suppression: 3 lanes hold keep-words, one-ahead prefetch,
    // dep chain = shuffle + ALU (no serial LDS latency)
    if (tid < 64) {
        const int l = tid;
        u64 kw   = (l < 3) ? keepw[l]  : 0ull;
        u64 scur = (l < 3) ? sup[0][l] : 0ull;
        for (int i = 0; i < MAXN; ++i) {
            u64 snext = (l < 3 && i + 1 < MAXN) ? sup[i + 1][l] : 0ull;
            u64 kwwi = __shfl(kw, i >> 6);
            if ((kwwi >> (i & 63)) & 1ull) {
                int lo = l * 64;
                u64 allow;
                if (i < lo)            allow = ~0ull;
                else if (i - lo >= 63) allow = 0ull;
                else                   allow = ~((1ull << (i - lo + 1)) - 1ull);
                kw &= ~(scur & allow);
            }
            scur = snext;
        }
        if (l < 3) keepw[l] = kw;
    }
    __syncthreads();

    if (tid < MAXN) {
        bool kp = (keepw[tid >> 6] >> (tid & 63)) & 1ull;
        int o = b * MAXN + tid;
        float* oSc = out;
        float* oId = out + NB * MAXN;
        float* oBx = out + 2 * NB * MAXN;
        float* oKp = out + 2 * NB * MAXN + NB * MAXN * 4;
        oSc[o] = kp ? sc[tid] : 0.0f;
        oId[o] = kp ? (float)idv[tid] : 0.0f;
        oBx[o * 4 + 0] = kp ? bx0[tid] : 0.0f;
        oBx[o * 4 + 1] = kp ? bx1[tid] : 0.0f;
        oBx[o * 4 + 2] = kp ? bx2[tid] : 0.0f;
        oBx[o * 4 + 3] = kp ? bx3[tid] : 0.0f;
        oKp[o] = kp ? 1.0f : 0.0f;
    }
}

// ---------------------------------------------------------------------------
extern "C" void kernel_launch(void* const* d_in, const int* in_sizes, int n_in,
                              void* d_out, int out_size, void* d_ws, size_t ws_size,
                              hipStream_t stream)
{
    const float* cls[5]; const float* reg[5]; const float* ctr[5];
    for (int li = 0; li < 5; ++li) {
        cls[li] = (const float*)d_in[3 * li + 0];
        reg[li] = (const float*)d_in[3 * li + 1];
        ctr[li] = (const float*)d_in[3 * li + 2];
    }

    u64* cand = (u64*)d_ws;   // NB * NCHUNK * MAXN u64 = 825 KB

    dim3 g1(NCHUNK, NB);
    k_part<<<g1, 512, 0, stream>>>(cls[0], cls[1], cls[2], cls[3], cls[4],
                                   ctr[0], ctr[1], ctr[2], ctr[3], ctr[4],
                                   cand);
    k_final<<<NB, 1024, 0, stream>>>(cls[0], cls[1], cls[2], cls[3], cls[4],
                                     reg[0], reg[1], reg[2], reg[3], reg[4],
                                     cand, (float*)d_out);
}

// Round 6
// 254.233 us; speedup vs baseline: 1.8275x; 1.0657x over previous
//
#include <hip/hip_runtime.h>
#include <cstdint>
#include <cstddef>

#define NPTS 21824
#define NB   64
#define NCLS 20
#define MAXN 150
#define NCHUNK 11
#define CHSZ 2048
#define CAP  186          // per-chunk candidate cap (11*186 = 2046 <= 2048)

typedef unsigned long long u64;
typedef unsigned int u32;

// Levels: L0 [0,16384) d=128 s=8 | L1 [16384,20480) d=64 s=16
//         L2 [20480,21504) d=32 s=32 | L3 [21504,21760) d=16 s=64
//         L4 [21760,21824) d=8 s=128

// ---------------------------------------------------------------------------
// Greedy-bit threshold bisection: returns largest T with count(key>=T) >= MAXN,
// early-stopping once count <= cap. Keys live in registers (8/thread, 256 thr).
// One barrier per iteration (ping-pong wave-count buffer). All threads compute
// identical decisions -> uniform control flow.
// Key layout: bit63=0 (score sign), bits62..32 = score[30:0], bits31..15 = 0,
// bits14..0 = (21823-p).  Bits 31..15 are skipped.
// ---------------------------------------------------------------------------
__device__ __forceinline__ u64 bisect_threshold(const u64 (&key)[8], int total,
                                                int (*wcnt)[4], int cap)
{
    const int tid  = threadIdx.x;
    const int lane = tid & 63, wv = tid >> 6;
    u64 T = 0;
    int count = total;
    int it = 0;
    for (int bbit = 62; bbit >= 0; --bbit) {
        if (bbit == 31) bbit = 14;       // skip structurally-zero bits
        if (count <= cap) break;
        u64 Tt = T | (1ull << bbit);
        int c = 0;
        #pragma unroll
        for (int i = 0; i < 8; ++i) c += (key[i] >= Tt) ? 1 : 0;
        for (int off = 32; off; off >>= 1) c += __shfl_xor(c, off);
        if (lane == 0) wcnt[it & 1][wv] = c;
        __syncthreads();
        int tot = wcnt[it & 1][0] + wcnt[it & 1][1]
                + wcnt[it & 1][2] + wcnt[it & 1][3];
        if (tot >= MAXN) { T = Tt; count = tot; }
        ++it;
    }
    return T;
}

// ---------------------------------------------------------------------------
// K1: fused scores + per-(batch,chunk) candidate pruning (keep >=150, <=186).
// score = sqrt( (1/(1+expf(-max_c logit))) * (1/(1+expf(-ctr))) )
// (expf monotone => identical bits to max-of-sigmoids path that passed.)
// ---------------------------------------------------------------------------
__global__ __launch_bounds__(256) void k_part(
    const float* __restrict__ c0, const float* __restrict__ c1,
    const float* __restrict__ c2, const float* __restrict__ c3,
    const float* __restrict__ c4,
    const float* __restrict__ t0, const float* __restrict__ t1,
    const float* __restrict__ t2, const float* __restrict__ t3,
    const float* __restrict__ t4,
    u64* __restrict__ cand)
{
    __shared__ int wcnt[2][4];
    __shared__ int cnt;
    const int tid   = threadIdx.x;
    const int chunk = blockIdx.x;
    const int b     = blockIdx.y;
    const int pl    = tid * 8;            // 8 contiguous points per thread
    const int p0    = chunk * CHSZ + pl;

    u64 key[8];
    #pragma unroll
    for (int i = 0; i < 8; ++i) key[i] = 0;

    if (p0 < NPTS) {
        const float* cp; const float* tp; int base; size_t hw;
        if (p0 < 16384)      { cp = c0; tp = t0; base = 0;     hw = 16384; }
        else if (p0 < 20480) { cp = c1; tp = t1; base = 16384; hw = 4096;  }
        else if (p0 < 21504) { cp = c2; tp = t2; base = 20480; hw = 1024;  }
        else if (p0 < 21760) { cp = c3; tp = t3; base = 21504; hw = 256;   }
        else                 { cp = c4; tp = t4; base = 21760; hw = 64;    }
        int q = p0 - base;                // 8-aligned (all bases are)
        const float* cb = cp + (size_t)b * NCLS * hw + q;

        float4 m0 = *reinterpret_cast<const float4*>(cb);
        float4 m1 = *reinterpret_cast<const float4*>(cb + 4);
        for (int c = 1; c < NCLS; ++c) {
            float4 v0 = *reinterpret_cast<const float4*>(cb + (size_t)c * hw);
            float4 v1 = *reinterpret_cast<const float4*>(cb + (size_t)c * hw + 4);
            m0.x = fmaxf(m0.x, v0.x); m0.y = fmaxf(m0.y, v0.y);
            m0.z = fmaxf(m0.z, v0.z); m0.w = fmaxf(m0.w, v0.w);
            m1.x = fmaxf(m1.x, v1.x); m1.y = fmaxf(m1.y, v1.y);
            m1.z = fmaxf(m1.z, v1.z); m1.w = fmaxf(m1.w, v1.w);
        }
        const float* tb = tp + (size_t)b * hw + q;
        float4 q0 = *reinterpret_cast<const float4*>(tb);
        float4 q1 = *reinterpret_cast<const float4*>(tb + 4);

        float mm[8] = {m0.x, m0.y, m0.z, m0.w, m1.x, m1.y, m1.z, m1.w};
        float cc[8] = {q0.x, q0.y, q0.z, q0.w, q1.x, q1.y, q1.z, q1.w};
        #pragma unroll
        for (int i = 0; i < 8; ++i) {
            float best = 1.0f / (1.0f + expf(-mm[i]));
            float sct  = 1.0f / (1.0f + expf(-cc[i]));
            float sc   = sqrtf(__fmul_rn(best, sct));
            key[i] = ((u64)__float_as_uint(sc) << 32)
                   | (u32)(21823 - (p0 + i));
        }
    }

    u64 T = bisect_threshold(key, CHSZ, wcnt, CAP);

    if (tid == 0) cnt = 0;
    __syncthreads();
    u64* outp = cand + ((size_t)b * NCHUNK + chunk) * CAP;
    #pragma unroll
    for (int i = 0; i < 8; ++i) {
        if (key[i] >= T) {
            int pos = atomicAdd(&cnt, 1);
            if (pos < CAP) outp[pos] = key[i];
        }
    }
    __syncthreads();
    for (int i = cnt + tid; i < CAP; i += 256) outp[i] = 0;  // pad (ws poisoned)
}

// ---------------------------------------------------------------------------
// K2: merge 11x186 -> exact sorted top-150 (bisect + rank-sort), exact id
// recompute, decode, reference-exact class-offset NMS, outputs.
// ---------------------------------------------------------------------------
__global__ __launch_bounds__(256) void k_final(
    const float* __restrict__ c0, const float* __restrict__ c1,
    const float* __restrict__ c2, const float* __restrict__ c3,
    const float* __restrict__ c4,
    const float* __restrict__ r0, const float* __restrict__ r1,
    const float* __restrict__ r2, const float* __restrict__ r3,
    const float* __restrict__ r4,
    const u64* __restrict__ cand,
    float* __restrict__ out)
{
    const int NC2 = NCHUNK * CAP;   // 2046
    __shared__ int wcnt[2][4];
    __shared__ int cnt;
    __shared__ u64 win[CAP];
    __shared__ u64 srt[MAXN];
    __shared__ float bx0[MAXN], bx1[MAXN], bx2[MAXN], bx3[MAXN];
    __shared__ float ox1[MAXN], oy1[MAXN], ox2[MAXN], oy2[MAXN], area[MAXN];
    __shared__ float sc[MAXN];
    __shared__ int   idv[MAXN];
    __shared__ u64 sup[MAXN][3];
    __shared__ u64 keepw[3];
    __shared__ float shcmax;
    __shared__ float wmax[4];

    const int b = blockIdx.x, tid = threadIdx.x;

    u64 key[8];
    #pragma unroll
    for (int j = 0; j < 8; ++j) {
        int i = j * 256 + tid;
        key[j] = (i < NC2) ? cand[(size_t)b * NC2 + i] : 0ull;
    }

    u64 T = bisect_threshold(key, CHSZ, wcnt, CAP);

    if (tid == 0) cnt = 0;
    if (tid < MAXN) srt[tid] = 0ull;
    __syncthreads();
    #pragma unroll
    for (int j = 0; j < 8; ++j) {
        if (key[j] >= T) {
            int pos = atomicAdd(&cnt, 1);
            if (pos < CAP) win[pos] = key[j];
        }
    }
    __syncthreads();
    int C = min(cnt, CAP);
    if (tid < C) {
        u64 mk = win[tid]; int r = 0;
        for (int j = 0; j < C; ++j) r += (win[j] > mk) ? 1 : 0;
        if (r < MAXN) srt[r] = mk;    // distinct nonzero keys -> permutation
    }
    __syncthreads();

    // decode + exact id recompute for the 150 winners
    if (tid < MAXN) {
        u64 kk = srt[tid];
        sc[tid] = __uint_as_float((u32)(kk >> 32));
        int p   = 21823 - (int)(kk & 0x7FFFu);

        const float* rp; const float* cp; int base, dim, lg, st;
        if (p < 16384)      { rp = r0; cp = c0; base = 0;     dim = 128; lg = 7; st = 8;   }
        else if (p < 20480) { rp = r1; cp = c1; base = 16384; dim = 64;  lg = 6; st = 16;  }
        else if (p < 21504) { rp = r2; cp = c2; base = 20480; dim = 32;  lg = 5; st = 32;  }
        else if (p < 21760) { rp = r3; cp = c3; base = 21504; dim = 16;  lg = 4; st = 64;  }
        else                { rp = r4; cp = c4; base = 21760; dim = 8;   lg = 3; st = 128; }

        int q = p - base;
        size_t hw = (size_t)dim * dim;

        // exact argmax over sigmoids, first max wins (reference semantics)
        const float* cb = cp + (size_t)b * NCLS * hw + q;
        float best = -1.0f; int bi = 0;
        for (int c = 0; c < NCLS; ++c) {
            float v  = cb[(size_t)c * hw];
            float sg = 1.0f / (1.0f + expf(-v));
            if (sg > best) { best = sg; bi = c; }
        }
        idv[tid] = bi + 1;

        int y = q >> lg;
        int x = q & (dim - 1);
        float s  = (float)st;
        float cx = (float)(x * st + (st >> 1));
        float cy = (float)(y * st + (st >> 1));
        const float* rg = rp + (size_t)b * 4 * hw + q;
        float a0 = rg[0], a1 = rg[hw], a2 = rg[2 * hw], a3 = rg[3 * hw];
        bx0[tid] = __fsub_rn(cx, __fmul_rn(a0, s));
        bx1[tid] = __fsub_rn(cy, __fmul_rn(a1, s));
        bx2[tid] = __fadd_rn(cx, __fmul_rn(a2, s));
        bx3[tid] = __fadd_rn(cy, __fmul_rn(a3, s));
    }
    __syncthreads();

    // coord_max over valid boxes — shuffle reduce, 4 wave maxes
    float m = -INFINITY;
    if (tid < MAXN && sc[tid] > 0.05f)
        m = fmaxf(fmaxf(bx0[tid], bx1[tid]), fmaxf(bx2[tid], bx3[tid]));
    #pragma unroll
    for (int off = 32; off >= 1; off >>= 1) m = fmaxf(m, __shfl_xor(m, off));
    if ((tid & 63) == 0) wmax[tid >> 6] = m;
    // valid mask via ballot (waves 0..2)
    if (tid < 192) {
        bool val = (tid < MAXN) && (sc[tid] > 0.05f);
        u64 mask = __ballot(val);
        if ((tid & 63) == 0) keepw[tid >> 6] = mask;
    }
    __syncthreads();
    if (tid == 0) {
        float mm = fmaxf(fmaxf(wmax[0], wmax[1]), fmaxf(wmax[2], wmax[3]));
        shcmax = isfinite(mm) ? mm : 0.0f;
    }
    __syncthreads();

    float cm1 = __fadd_rn(shcmax, 1.0f);
    if (tid < MAXN) {
        float off = __fmul_rn((float)idv[tid], cm1);
        float X1 = __fadd_rn(bx0[tid], off);
        float Y1 = __fadd_rn(bx1[tid], off);
        float X2 = __fadd_rn(bx2[tid], off);
        float Y2 = __fadd_rn(bx3[tid], off);
        ox1[tid] = X1; oy1[tid] = Y1; ox2[tid] = X2; oy2[tid] = Y2;
        area[tid] = __fmul_rn(__fadd_rn(__fsub_rn(X2, X1), 1.0f),
                              __fadd_rn(__fsub_rn(Y2, Y1), 1.0f));
    }
    __syncthreads();

    // suppression bitmask rows: 450 tasks over 256 threads
    for (int t = tid; t < MAXN * 3; t += 256) {
        int i = t / 3;
        int w = t - i * 3;
        float x1i = ox1[i], y1i = oy1[i], x2i = ox2[i], y2i = oy2[i], ai = area[i];
        u64 bits = 0ull;
        for (int e = 0; e < 64; ++e) {
            int j = w * 64 + e;
            if (j >= MAXN) break;
            float xmin = fmaxf(x1i, ox1[j]);
            float ymin = fmaxf(y1i, oy1[j]);
            float xmax = fminf(x2i, ox2[j]);
            float ymax = fminf(y2i, oy2[j]);
            float ow = fmaxf(__fsub_rn(xmax, xmin), 0.0f);
            float oh = fmaxf(__fsub_rn(ymax, ymin), 0.0f);
            float ov = __fmul_rn(ow, oh);
            float un = fmaxf(__fsub_rn(__fadd_rn(ai, area[j]), ov), 1e-10f);
            float iou = __fdiv_rn(ov, un);
            if (iou > 0.6f) bits |= (1ull << e);
        }
        sup[i][w] = bits;
    }
    __syncthreads();

    // greedy suppression: 3 lanes hold keep-words, one-ahead prefetch
    if (tid < 64) {
        const int l = tid;
        u64 kw   = (l < 3) ? keepw[l]  : 0ull;
        u64 scur = (l < 3) ? sup[0][l] : 0ull;
        for (int i = 0; i < MAXN; ++i) {
            u64 snext = (l < 3 && i + 1 < MAXN) ? sup[i + 1][l] : 0ull;
            u64 kwwi = __shfl(kw, i >> 6);
            if ((kwwi >> (i & 63)) & 1ull) {
                int lo = l * 64;
                u64 allow;
                if (i < lo)            allow = ~0ull;
                else if (i - lo >= 63) allow = 0ull;
                else                   allow = ~((1ull << (i - lo + 1)) - 1ull);
                kw &= ~(scur & allow);
            }
            scur = snext;
        }
        if (l < 3) keepw[l] = kw;
    }
    __syncthreads();

    if (tid < MAXN) {
        bool kp = (keepw[tid >> 6] >> (tid & 63)) & 1ull;
        int o = b * MAXN + tid;
        float* oSc = out;
        float* oId = out + NB * MAXN;
        float* oBx = out + 2 * NB * MAXN;
        float* oKp = out + 2 * NB * MAXN + NB * MAXN * 4;
        oSc[o] = kp ? sc[tid] : 0.0f;
        oId[o] = kp ? (float)idv[tid] : 0.0f;
        oBx[o * 4 + 0] = kp ? bx0[tid] : 0.0f;
        oBx[o * 4 + 1] = kp ? bx1[tid] : 0.0f;
        oBx[o * 4 + 2] = kp ? bx2[tid] : 0.0f;
        oBx[o * 4 + 3] = kp ? bx3[tid] : 0.0f;
        oKp[o] = kp ? 1.0f : 0.0f;
    }
}

// ---------------------------------------------------------------------------
extern "C" void kernel_launch(void* const* d_in, const int* in_sizes, int n_in,
                              void* d_out, int out_size, void* d_ws, size_t ws_size,
                              hipStream_t stream)
{
    const float* cls[5]; const float* reg[5]; const float* ctr[5];
    for (int li = 0; li < 5; ++li) {
        cls[li] = (const float*)d_in[3 * li + 0];
        reg[li] = (const float*)d_in[3 * li + 1];
        ctr[li] = (const float*)d_in[3 * li + 2];
    }

    u64* cand = (u64*)d_ws;   // NB * NCHUNK * CAP u64 ≈ 1.05 MB

    dim3 g1(NCHUNK, NB);
    k_part<<<g1, 256, 0, stream>>>(cls[0], cls[1], cls[2], cls[3], cls[4],
                                   ctr[0], ctr[1], ctr[2], ctr[3], ctr[4],
                                   cand);
    k_final<<<NB, 256, 0, stream>>>(cls[0], cls[1], cls[2], cls[3], cls[4],
                                    reg[0], reg[1], reg[2], reg[3], reg[4],
                                    cand, (float*)d_out);
}